// Round 6
// baseline (193.019 us; speedup 1.0000x reference)
//
#include <hip/hip_runtime.h>

#define SPK 1024
#define UTT 64
#define DIM 256
#define EPSV 1e-5f
#define NROW (SPK * UTT)
#define LOG2E 1.44269504f

typedef __attribute__((ext_vector_type(8))) short short8;   // 8 bf16 (4 VGPRs)
typedef __attribute__((ext_vector_type(4))) float f32x4;    // MFMA accumulator

__device__ __forceinline__ unsigned short f2bf(float f) {
    unsigned int u = __builtin_bit_cast(unsigned int, f);
    u += 0x7fffu + ((u >> 16) & 1u);          // round-to-nearest-even
    return (unsigned short)(u >> 16);
}

// K1: one block (256 thr) per speaker. Phase A: csum + c_incl (bf16) + ||csum||^2.
// Phase B: 4 lanes per row (quad-reduce), x re-read is L2-hot (same 64 KB just
// read), writes e_n (bf16) and pre-scaled diagonal logit texcl = w*sim_excl + b.
__global__ __launch_bounds__(256)
void k_prep(const float* __restrict__ x,
            unsigned short* __restrict__ cincl,
            unsigned short* __restrict__ en,
            float* __restrict__ texcl,
            const float* __restrict__ wp, const float* __restrict__ bp) {
    __shared__ float4 sc4[256];
    __shared__ float4 cs4[64];
    __shared__ float sccs;
    int s = blockIdx.x, tid = threadIdx.x;
    int dq = tid & 63, ug = tid >> 6;
    const float4* x4 = (const float4*)(x + (size_t)s * UTT * DIM);

    // Phase A: column sums over the 64 utterances (coalesced 1KB/instr)
    float4 p = {0.f, 0.f, 0.f, 0.f};
#pragma unroll
    for (int i = 0; i < 16; ++i) {
        float4 v = x4[(ug * 16 + i) * 64 + dq];
        p.x += v.x; p.y += v.y; p.z += v.z; p.w += v.w;
    }
    sc4[tid] = p;
    __syncthreads();
    if (tid < 64) {
        float4 a = sc4[dq], b2 = sc4[64 + dq], c = sc4[128 + dq], d = sc4[192 + dq];
        float4 cs = {a.x + b2.x + c.x + d.x, a.y + b2.y + c.y + d.y,
                     a.z + b2.z + c.z + d.z, a.w + b2.w + c.w + d.w};
        cs4[dq] = cs;
        float s2 = cs.x * cs.x + cs.y * cs.y + cs.z * cs.z + cs.w * cs.w;
#pragma unroll
        for (int o = 1; o < 64; o <<= 1) s2 += __shfl_xor(s2, o);
        if (tid == 0) sccs = s2;
        // c_incl = (csum/U)/(||csum/U||+eps) == csum/(||csum|| + U*eps)
        float inv = 1.f / (sqrtf(s2) + UTT * EPSV);
        ushort4 ob = {f2bf(cs.x * inv), f2bf(cs.y * inv),
                      f2bf(cs.z * inv), f2bf(cs.w * inv)};
        *(ushort4*)(cincl + (size_t)s * DIM + dq * 4) = ob;
    }
    __syncthreads();
    float scc = sccs;
    float w = wp[0], b = bp[0];

    // Phase B: row = tid>>2 (64 rows), sub = tid&3 (4 lanes per row).
    int row = tid >> 2, sub = tid & 3;
    const float4* xr = x4 + row * 64;
    float4 xv[16];
    float sx = 0.f, sc = 0.f;
#pragma unroll
    for (int i = 0; i < 16; ++i) {
        float4 v = xr[i * 4 + sub];
        float4 cv = cs4[i * 4 + sub];
        xv[i] = v;
        sx += v.x * v.x + v.y * v.y + v.z * v.z + v.w * v.w;
        sc += v.x * cv.x + v.y * cv.y + v.z * cv.z + v.w * cv.w;
    }
    // quad reduce: all 4 lanes of the row end up with the totals
    sx += __shfl_xor(sx, 1); sx += __shfl_xor(sx, 2);
    sc += __shfl_xor(sc, 1); sc += __shfl_xor(sc, 2);
    float nx = sqrtf(sx);
    float inv = 1.f / (nx + EPSV);
    unsigned short* er = en + (size_t)(s * UTT + row) * DIM;
#pragma unroll
    for (int i = 0; i < 16; ++i) {
        ushort4 ob = {f2bf(xv[i].x * inv), f2bf(xv[i].y * inv),
                      f2bf(xv[i].z * inv), f2bf(xv[i].w * inv)};
        *(ushort4*)(er + (i * 4 + sub) * 4) = ob;
    }
    if (sub == 0) {
        // sim_excl = x.(csum-x) / ((||x||+eps)(||csum-x||+63eps))
        float num = sc - sx;
        float e2 = fmaxf(scc - 2.f * sc + sx, 0.f);
        float sim = num / ((nx + EPSV) * (sqrtf(e2) + (UTT - 1) * EPSV));
        texcl[s * UTT + row] = fmaf(sim, w, b);
    }
}

// K2: block = 1 speaker (4 waves), wave = all 64 rows x a 256-col slice.
// A (en, this speaker) read once per block; B (cincl) double-buffered via
// global_load_lds: chunk = 16 cols per wave (one ntile), 2 x 32 KB LDS,
// swizzled conflict-free ds_read_b128. Grid 1024 -> 2 blocks/CU resident
// (8 waves/CU) so inter-block overlap hides barriers/LDS/VALU latency.
// exp2-domain softmax with fixed max M; 4 col-slices combined via LDS.
__global__ __launch_bounds__(256, 2)
void k_main(const unsigned short* __restrict__ en,
            const unsigned short* __restrict__ cincl,
            const float* __restrict__ texcl,
            const float* __restrict__ wp, const float* __restrict__ bp,
            float* __restrict__ out) {
    __shared__ unsigned short Bs[2][32 * 512];   // 2 x 32 slots x 1 KB = 64 KB
    __shared__ float sl[4][UTT];                 // per-wave row partials
    int tid = threadIdx.x, wave = tid >> 6, lane = tid & 63;
    int quad = lane >> 4, lx = lane & 15;
    int s = blockIdx.x;                          // this block's speaker
    int col0 = wave * 256;                       // this wave's column slice
    float w = wp[0], b = bp[0];
    float M  = fabsf(w) * 1.0625f + b;           // >= any logit (|sim| <= ~1)
    float wl = w * LOG2E;
    float bl = (b - M) * LOG2E;                  // exp(v-M) = exp2(acc*wl + bl)

    // stage chunk c into buf: slot p = wave*8 + kt (1 KB each). Lane ℓ supplies
    // B[col = col0 + c*16 + (ℓ&15)][k = kt*32 + (ℓ>>4)*8 .. +8]; LDS = base + ℓ*16.
    auto stage = [&](int c, int buf) {
#pragma unroll
        for (int kt = 0; kt < 8; ++kt) {
            const unsigned short* g = cincl +
                (size_t)(col0 + c * 16 + lx) * DIM + kt * 32 + quad * 8;
            __builtin_amdgcn_global_load_lds(
                (const __attribute__((address_space(1))) void*)g,
                (__attribute__((address_space(3))) void*)(&Bs[buf][(wave * 8 + kt) * 512]),
                16, 0, 0);
        }
    };

    stage(0, 0);

    // A fragments (all 64 rows of speaker s) while staging is in flight
    const unsigned short* abase = en + (size_t)s * UTT * DIM;
    short8 af[4][8];
#pragma unroll
    for (int mt = 0; mt < 4; ++mt)
#pragma unroll
        for (int kt = 0; kt < 8; ++kt)
            af[mt][kt] = *(const short8*)(abase + (mt * 16 + lx) * DIM + kt * 32 + quad * 8);

    float l[16];
#pragma unroll
    for (int i = 0; i < 16; ++i) l[i] = 0.f;

    int dc  = (s - col0) >> 4;                   // diag chunk if in [0,16)
    int dlx = s & 15;

    for (int c = 0; c < 16; ++c) {
        int buf = c & 1;
        __syncthreads();                         // stage(c) complete
        if (c < 15) stage(c + 1, buf ^ 1);       // async; hidden by compute(c)
        short8 bf[8];
#pragma unroll
        for (int kt = 0; kt < 8; ++kt)
            bf[kt] = *(const short8*)(&Bs[buf][(wave * 8 + kt) * 512 + lane * 8]);
        f32x4 aA[4] = {{0.f,0.f,0.f,0.f},{0.f,0.f,0.f,0.f},
                       {0.f,0.f,0.f,0.f},{0.f,0.f,0.f,0.f}};
        f32x4 aB[4] = {{0.f,0.f,0.f,0.f},{0.f,0.f,0.f,0.f},
                       {0.f,0.f,0.f,0.f},{0.f,0.f,0.f,0.f}};
#pragma unroll
        for (int kt = 0; kt < 4; ++kt) {         // 8 interleaved MFMA chains
            aA[0] = __builtin_amdgcn_mfma_f32_16x16x32_bf16(af[0][kt], bf[kt], aA[0], 0, 0, 0);
            aA[1] = __builtin_amdgcn_mfma_f32_16x16x32_bf16(af[1][kt], bf[kt], aA[1], 0, 0, 0);
            aA[2] = __builtin_amdgcn_mfma_f32_16x16x32_bf16(af[2][kt], bf[kt], aA[2], 0, 0, 0);
            aA[3] = __builtin_amdgcn_mfma_f32_16x16x32_bf16(af[3][kt], bf[kt], aA[3], 0, 0, 0);
            aB[0] = __builtin_amdgcn_mfma_f32_16x16x32_bf16(af[0][kt+4], bf[kt+4], aB[0], 0, 0, 0);
            aB[1] = __builtin_amdgcn_mfma_f32_16x16x32_bf16(af[1][kt+4], bf[kt+4], aB[1], 0, 0, 0);
            aB[2] = __builtin_amdgcn_mfma_f32_16x16x32_bf16(af[2][kt+4], bf[kt+4], aB[2], 0, 0, 0);
            aB[3] = __builtin_amdgcn_mfma_f32_16x16x32_bf16(af[3][kt+4], bf[kt+4], aB[3], 0, 0, 0);
        }
#pragma unroll
        for (int mt = 0; mt < 4; ++mt)
#pragma unroll
            for (int r = 0; r < 4; ++r)
                l[mt * 4 + r] += exp2f(fmaf(aA[mt][r] + aB[mt][r], wl, bl));
        if (c == dc) {                           // wave-uniform: undo diag col
#pragma unroll
            for (int mt = 0; mt < 4; ++mt)
#pragma unroll
                for (int r = 0; r < 4; ++r) {
                    float e = exp2f(fmaf(aA[mt][r] + aB[mt][r], wl, bl));
                    if (lx == dlx) l[mt * 4 + r] -= e;
                }
        }
    }

    // reduce over the 16 col-lanes; rows live at (quad, mt, r)
#pragma unroll
    for (int o = 1; o < 16; o <<= 1)
#pragma unroll
        for (int i = 0; i < 16; ++i) l[i] += __shfl_xor(l[i], o);
    if (lx == 0)
#pragma unroll
        for (int mt = 0; mt < 4; ++mt)
#pragma unroll
            for (int r = 0; r < 4; ++r)
                sl[wave][mt * 16 + quad * 4 + r] = l[mt * 4 + r];
    __syncthreads();

    if (wave == 0) {                             // lane = row; finalize lse
        float lt = sl[0][lane] + sl[1][lane] + sl[2][lane] + sl[3][lane];
        float tex = texcl[s * UTT + lane];       // fp32 diag logit
        float lsum = lt + exp2f((tex - M) * LOG2E);
        float contrib = (M + __logf(lsum)) - tex;   // lse - target
#pragma unroll
        for (int o = 1; o < 64; o <<= 1) contrib += __shfl_xor(contrib, o);
        if (lane == 0) atomicAdd(out, contrib * (1.f / NROW));
    }
}

extern "C" void kernel_launch(void* const* d_in, const int* in_sizes, int n_in,
                              void* d_out, int out_size, void* d_ws, size_t ws_size,
                              hipStream_t stream) {
    const float* x  = (const float*)d_in[0];
    const float* wp = (const float*)d_in[1];
    const float* bp = (const float*)d_in[2];
    char* ws = (char*)d_ws;
    unsigned short* cincl = (unsigned short*)ws;                    // @0,    512 KB
    float* texcl          = (float*)(ws + (1u << 19));              // @512K, 256 KB
    unsigned short* en    = (unsigned short*)(ws + (1u << 20));     // @1M,   32 MB
    float* out = (float*)d_out;

    hipMemsetAsync(d_out, 0, sizeof(float), stream);
    k_prep<<<SPK, 256, 0, stream>>>(x, cincl, en, texcl, wp, bp);
    k_main<<<SPK, 256, 0, stream>>>(en, cincl, texcl, wp, bp, out);
}

// Round 8
// 166.374 us; speedup vs baseline: 1.1601x; 1.1601x over previous
//
#include <hip/hip_runtime.h>

#define SPK 1024
#define UTT 64
#define DIM 256
#define EPSV 1e-5f
#define NROW (SPK * UTT)
#define NSL 8            // column slices (128 cols each)
#define LOG2E 1.44269504f

typedef __attribute__((ext_vector_type(8))) short short8;   // 8 bf16 (4 VGPRs)
typedef __attribute__((ext_vector_type(4))) float f32x4;    // MFMA accumulator

__device__ __forceinline__ unsigned short f2bf(float f) {
    unsigned int u = __builtin_bit_cast(unsigned int, f);
    u += 0x7fffu + ((u >> 16) & 1u);          // round-to-nearest-even
    return (unsigned short)(u >> 16);
}

// K1: one block (256 thr) per speaker. Phase A: csum + c_incl (bf16) + ||csum||^2.
// Phase B: 4 lanes per row (quad-reduce), x re-read L2-hot, writes e_n (bf16)
// and pre-scaled diagonal logit texcl = w*sim_excl + b.
__global__ __launch_bounds__(256)
void k_prep(const float* __restrict__ x,
            unsigned short* __restrict__ cincl,
            unsigned short* __restrict__ en,
            float* __restrict__ texcl,
            const float* __restrict__ wp, const float* __restrict__ bp) {
    __shared__ float4 sc4[256];
    __shared__ float4 cs4[64];
    __shared__ float sccs;
    int s = blockIdx.x, tid = threadIdx.x;
    int dq = tid & 63, ug = tid >> 6;
    const float4* x4 = (const float4*)(x + (size_t)s * UTT * DIM);

    // Phase A: column sums over the 64 utterances (coalesced 1KB/instr)
    float4 p = {0.f, 0.f, 0.f, 0.f};
#pragma unroll
    for (int i = 0; i < 16; ++i) {
        float4 v = x4[(ug * 16 + i) * 64 + dq];
        p.x += v.x; p.y += v.y; p.z += v.z; p.w += v.w;
    }
    sc4[tid] = p;
    __syncthreads();
    if (tid < 64) {
        float4 a = sc4[dq], b2 = sc4[64 + dq], c = sc4[128 + dq], d = sc4[192 + dq];
        float4 cs = {a.x + b2.x + c.x + d.x, a.y + b2.y + c.y + d.y,
                     a.z + b2.z + c.z + d.z, a.w + b2.w + c.w + d.w};
        cs4[dq] = cs;
        float s2 = cs.x * cs.x + cs.y * cs.y + cs.z * cs.z + cs.w * cs.w;
#pragma unroll
        for (int o = 1; o < 64; o <<= 1) s2 += __shfl_xor(s2, o);
        if (tid == 0) sccs = s2;
        // c_incl = (csum/U)/(||csum/U||+eps) == csum/(||csum|| + U*eps)
        float inv = 1.f / (sqrtf(s2) + UTT * EPSV);
        ushort4 ob = {f2bf(cs.x * inv), f2bf(cs.y * inv),
                      f2bf(cs.z * inv), f2bf(cs.w * inv)};
        *(ushort4*)(cincl + (size_t)s * DIM + dq * 4) = ob;
    }
    __syncthreads();
    float scc = sccs;
    float w = wp[0], b = bp[0];

    // Phase B: row = tid>>2 (64 rows), sub = tid&3 (4 lanes per row).
    int row = tid >> 2, sub = tid & 3;
    const float4* xr = x4 + row * 64;
    float4 xv[16];
    float sx = 0.f, sc = 0.f;
#pragma unroll
    for (int i = 0; i < 16; ++i) {
        float4 v = xr[i * 4 + sub];
        float4 cv = cs4[i * 4 + sub];
        xv[i] = v;
        sx += v.x * v.x + v.y * v.y + v.z * v.z + v.w * v.w;
        sc += v.x * cv.x + v.y * cv.y + v.z * cv.z + v.w * cv.w;
    }
    // quad reduce: all 4 lanes of the row end up with the totals
    sx += __shfl_xor(sx, 1); sx += __shfl_xor(sx, 2);
    sc += __shfl_xor(sc, 1); sc += __shfl_xor(sc, 2);
    float nx = sqrtf(sx);
    float inv = 1.f / (nx + EPSV);
    unsigned short* er = en + (size_t)(s * UTT + row) * DIM;
#pragma unroll
    for (int i = 0; i < 16; ++i) {
        ushort4 ob = {f2bf(xv[i].x * inv), f2bf(xv[i].y * inv),
                      f2bf(xv[i].z * inv), f2bf(xv[i].w * inv)};
        *(ushort4*)(er + (i * 4 + sub) * 4) = ob;
    }
    if (sub == 0) {
        // sim_excl = x.(csum-x) / ((||x||+eps)(||csum-x||+63eps))
        float num = sc - sx;
        float e2 = fmaxf(scc - 2.f * sc + sx, 0.f);
        float sim = num / ((nx + EPSV) * (sqrtf(e2) + (UTT - 1) * EPSV));
        texcl[s * UTT + row] = fmaf(sim, w, b);
    }
}

// K2: block = 4 speakers x one 128-col slice; B slice (64 KB) staged into LDS
// ONCE (one barrier total), then pure ds_read+MFMA+exp2. XCD swizzle: bid%8 =
// XCD (round-robin dispatch heuristic); cs = j&7, sg = xcd + 8*(j>>3) so the
// 8 slices of a speaker group run back-to-back on ONE XCD -> the group's A
// tile (128 KB) is L2-hot on re-read (hot set ~8 groups x 128 KB + 512 KB B
// << 4 MB per-XCD L2). A hits HBM once total. exp2-domain softmax.
__global__ __launch_bounds__(256, 2)
void k_main(const unsigned short* __restrict__ en,
            const unsigned short* __restrict__ cincl,
            float* __restrict__ partial,
            const float* __restrict__ wp, const float* __restrict__ bp) {
    __shared__ unsigned short Bs[64 * 512];      // 64 slots x 1 KB = 64 KB
    int tid = threadIdx.x, wave = tid >> 6, lane = tid & 63;
    int quad = lane >> 4, lx = lane & 15;
    int bid = blockIdx.x;
    int xcd = bid & 7, j = bid >> 3;             // j in [0,256)
    int cs = j & 7;                              // column slice (0..7)
    int sg = xcd + 8 * (j >> 3);                 // speaker group (0..255)
    int sw = sg * 4 + wave;                      // this wave's speaker
    float w = wp[0], b = bp[0];
    float M  = fabsf(w) * 1.0625f + b;           // >= any logit (|sim| <= ~1)
    float wl = w * LOG2E;
    float bl = (b - M) * LOG2E;                  // exp(v-M) = exp2(acc*wl + bl)

    // stage B: slot p=(nt*8+kt): lane ℓ holds B[n=ℓ&15][k=(ℓ>>4)*8..] for tile
#pragma unroll
    for (int i = 0; i < 16; ++i) {
        int p = wave * 16 + i;
        int nt = p >> 3, kt = p & 7;
        const unsigned short* g = cincl +
            (size_t)(cs * 128 + nt * 16 + lx) * DIM + kt * 32 + quad * 8;
        __builtin_amdgcn_global_load_lds(
            (const __attribute__((address_space(1))) void*)g,
            (__attribute__((address_space(3))) void*)(Bs + p * 512), 16, 0, 0);
    }

    // A fragments (64 rows of speaker sw) while staging is in flight
    const unsigned short* abase = en + (size_t)sw * UTT * DIM;
    short8 af[4][8];
#pragma unroll
    for (int mt = 0; mt < 4; ++mt)
#pragma unroll
        for (int kt = 0; kt < 8; ++kt)
            af[mt][kt] = *(const short8*)(abase + (mt * 16 + lx) * DIM + kt * 32 + quad * 8);

    float l[16];
#pragma unroll
    for (int i = 0; i < 16; ++i) l[i] = 0.f;

    __syncthreads();

    int dnt = (sw >> 4) - cs * 8;                // diag ntile if in [0,8)
    int dlx = sw & 15;

    for (int nt = 0; nt < 8; ++nt) {
        short8 bf[8];
#pragma unroll
        for (int kt = 0; kt < 8; ++kt)
            bf[kt] = *(const short8*)(Bs + (nt * 8 + kt) * 512 + lane * 8);
        f32x4 aA[4] = {{0.f,0.f,0.f,0.f},{0.f,0.f,0.f,0.f},
                       {0.f,0.f,0.f,0.f},{0.f,0.f,0.f,0.f}};
        f32x4 aB[4] = {{0.f,0.f,0.f,0.f},{0.f,0.f,0.f,0.f},
                       {0.f,0.f,0.f,0.f},{0.f,0.f,0.f,0.f}};
#pragma unroll
        for (int kt = 0; kt < 4; ++kt) {         // 8 interleaved MFMA chains
            aA[0] = __builtin_amdgcn_mfma_f32_16x16x32_bf16(af[0][kt], bf[kt], aA[0], 0, 0, 0);
            aA[1] = __builtin_amdgcn_mfma_f32_16x16x32_bf16(af[1][kt], bf[kt], aA[1], 0, 0, 0);
            aA[2] = __builtin_amdgcn_mfma_f32_16x16x32_bf16(af[2][kt], bf[kt], aA[2], 0, 0, 0);
            aA[3] = __builtin_amdgcn_mfma_f32_16x16x32_bf16(af[3][kt], bf[kt], aA[3], 0, 0, 0);
            aB[0] = __builtin_amdgcn_mfma_f32_16x16x32_bf16(af[0][kt+4], bf[kt+4], aB[0], 0, 0, 0);
            aB[1] = __builtin_amdgcn_mfma_f32_16x16x32_bf16(af[1][kt+4], bf[kt+4], aB[1], 0, 0, 0);
            aB[2] = __builtin_amdgcn_mfma_f32_16x16x32_bf16(af[2][kt+4], bf[kt+4], aB[2], 0, 0, 0);
            aB[3] = __builtin_amdgcn_mfma_f32_16x16x32_bf16(af[3][kt+4], bf[kt+4], aB[3], 0, 0, 0);
        }
#pragma unroll
        for (int mt = 0; mt < 4; ++mt)
#pragma unroll
            for (int r = 0; r < 4; ++r)
                l[mt * 4 + r] += exp2f(fmaf(aA[mt][r] + aB[mt][r], wl, bl));
        if (nt == dnt) {                          // wave-uniform: undo diag col
#pragma unroll
            for (int mt = 0; mt < 4; ++mt)
#pragma unroll
                for (int r = 0; r < 4; ++r) {
                    float e = exp2f(fmaf(aA[mt][r] + aB[mt][r], wl, bl));
                    if (lx == dlx) l[mt * 4 + r] -= e;
                }
        }
    }

    // reduce over the 16 col-lanes; rows live at (quad, mt, r)
#pragma unroll
    for (int o = 1; o < 16; o <<= 1)
#pragma unroll
        for (int i = 0; i < 16; ++i) l[i] += __shfl_xor(l[i], o);
    if (lx == 0)
#pragma unroll
        for (int mt = 0; mt < 4; ++mt)
#pragma unroll
            for (int r = 0; r < 4; ++r)
                partial[(size_t)cs * NROW + (size_t)sw * UTT + mt * 16 + quad * 4 + r]
                    = l[mt * 4 + r];
}

// K3: combine the 8 slice partials per row, logsumexp, mean-reduce.
__global__ __launch_bounds__(256)
void k_final(const float* __restrict__ partial, const float* __restrict__ texcl,
             const float* __restrict__ wp, const float* __restrict__ bp,
             float* __restrict__ out) {
    int row = blockIdx.x * 256 + threadIdx.x;
    float w = wp[0], b = bp[0];
    float M = fabsf(w) * 1.0625f + b;
    float t = 0.f;
#pragma unroll
    for (int sl = 0; sl < NSL; ++sl) t += partial[(size_t)sl * NROW + row];
    float tex = texcl[row];
    float c = (M + __logf(t + exp2f((tex - M) * LOG2E))) - tex;   // lse - target
#pragma unroll
    for (int o = 1; o < 64; o <<= 1) c += __shfl_xor(c, o);
    __shared__ float red[4];
    if ((threadIdx.x & 63) == 0) red[threadIdx.x >> 6] = c;
    __syncthreads();
    if (threadIdx.x == 0)
        atomicAdd(out, (red[0] + red[1] + red[2] + red[3]) * (1.f / NROW));
}

extern "C" void kernel_launch(void* const* d_in, const int* in_sizes, int n_in,
                              void* d_out, int out_size, void* d_ws, size_t ws_size,
                              hipStream_t stream) {
    const float* x  = (const float*)d_in[0];
    const float* wp = (const float*)d_in[1];
    const float* bp = (const float*)d_in[2];
    char* ws = (char*)d_ws;
    unsigned short* cincl = (unsigned short*)ws;                    // @0,    512 KB
    float* texcl          = (float*)(ws + (1u << 19));              // @512K, 256 KB
    float* partial        = (float*)(ws + (3u << 20));              // @3M,   2 MB
    unsigned short* en    = (unsigned short*)(ws + (8u << 20));     // @8M,   32 MB
    float* out = (float*)d_out;

    hipMemsetAsync(d_out, 0, sizeof(float), stream);
    k_prep <<<SPK, 256, 0, stream>>>(x, cincl, en, texcl, wp, bp);
    k_main <<<(SPK / 4) * NSL, 256, 0, stream>>>(en, cincl, partial, wp, bp);
    k_final<<<NROW / 256, 256, 0, stream>>>(partial, texcl, wp, bp, out);
}